// Round 15
// baseline (486.135 us; speedup 1.0000x reference)
//
#include <hip/hip_runtime.h>
#include <hip/hip_bf16.h>
#include <hip/hip_cooperative_groups.h>

namespace cg = cooperative_groups;

#define NN 100000
#define EE 3200000
#define GG 128
#define IN_DIM 16
#define HDIM 64
#define CDIM 4

#define RN 256                    // nodes per bucket
#define NB ((NN + RN - 1) / RN)   // 391 buckets == edge chunks
#define CH 8192                   // edges per chunk

typedef unsigned short u16;
typedef unsigned int u32;
typedef __attribute__((ext_vector_type(8))) short bf16x8;
typedef __attribute__((ext_vector_type(4))) float f32x4;

__device__ __forceinline__ float bf_lo(u32 w) { return __uint_as_float(w << 16); }
__device__ __forceinline__ float bf_hi(u32 w) { return __uint_as_float(w & 0xFFFF0000u); }
__device__ __forceinline__ u16 f2bf(float f) {
    u32 x = __float_as_uint(f);
    return (u16)((x + 0x7FFFu + ((x >> 16) & 1u)) >> 16);   // RNE
}
__device__ __forceinline__ float rdlane(float v, int lane) {
    return __int_as_float(__builtin_amdgcn_readlane(__float_as_int(v), lane));
}

// ---------------- fused CSR build (cooperative): hist -> scan -> partition -> fill ----
// 391 blocks x 512 thr; block b is both edge-chunk b (phases 1,3) and bucket b (phase 4).
// Edge list is read exactly once (phase 1); packed edges persist in registers across
// grid.sync; pairs stays L3-warm between phase 3 and phase 4.

__global__ __launch_bounds__(512) void build_k(const int* __restrict__ src,
                                               const int* __restrict__ dst,
                                               const float* __restrict__ x,
                                               int* __restrict__ bcnt,
                                               int* __restrict__ bucketBase,
                                               int* __restrict__ gcursor,
                                               u32* __restrict__ pairs,
                                               int* __restrict__ rowptr,
                                               float* __restrict__ dinv,
                                               int* __restrict__ srcS,
                                               u16* __restrict__ xs) {
    __shared__ int hist[NB];
    __shared__ int lbase[NB];
    __shared__ int gbase[NB];
    __shared__ int scanbuf[512];
    __shared__ u32 stag[CH];      // 32 KB
    __shared__ u16 stagb[CH];     // 16 KB
    __shared__ int sb[256];
    __shared__ int sdeg[256];
    __shared__ int lcur[256];
    __shared__ float sdinv[256];

    cg::grid_group grid = cg::this_grid();
    int t = threadIdx.x;
    int b = blockIdx.x;
    long e0 = (long)b * CH;
    int cnt = (int)min((long)CH, (long)EE - e0);

    // ---- phase 1: read chunk once, bin in registers + LDS hist, flush bucket counts --
    for (int i = t; i < NB; i += 512) hist[i] = 0;
    __syncthreads();
    int myb[16], myloc[16];
    u32 myp[16];
#pragma unroll
    for (int r = 0; r < 16; ++r) {
        int i = t + (r << 9);
        if (i < cnt) {
            int s = src[e0 + i], d = dst[e0 + i];
            int bb = d >> 8;
            myb[r] = bb;
            myp[r] = ((u32)s << 8) | (u32)(d & 255);
            myloc[r] = atomicAdd(&hist[bb], 1);
        } else {
            myb[r] = -1;
            myloc[r] = 0;
            myp[r] = 0;
        }
    }
    __syncthreads();
    for (int i = t; i < NB; i += 512) {
        int v = hist[i];
        if (v > 0) atomicAdd(&bcnt[i], v);
    }
    __threadfence();
    grid.sync();

    // ---- phase 2: block 0 scans bucket counts -> bucketBase, gcursor ----
    if (b == 0) {
        int c2 = (t < NB) ? bcnt[t] : 0;
        scanbuf[t] = c2;
        __syncthreads();
        for (int off = 1; off < 512; off <<= 1) {
            int v = (t >= off) ? scanbuf[t - off] : 0;
            __syncthreads();
            scanbuf[t] += v;
            __syncthreads();
        }
        if (t < NB) {
            int base = scanbuf[t] - c2;
            bucketBase[t] = base;
            gcursor[t] = base;
        }
        if (t == 0) bucketBase[NB] = EE;
    }
    __threadfence();
    grid.sync();

    // ---- phase 3: scatter chunk to bucket-grouped pairs ----
    scanbuf[t] = (t < NB) ? hist[t] : 0;
    __syncthreads();
    for (int off = 1; off < 512; off <<= 1) {
        int v = (t >= off) ? scanbuf[t - off] : 0;
        __syncthreads();
        scanbuf[t] += v;
        __syncthreads();
    }
    if (t < NB) {
        lbase[t] = scanbuf[t] - hist[t];
        gbase[t] = (hist[t] > 0) ? atomicAdd(&gcursor[t], hist[t]) : 0;
    }
    __syncthreads();
#pragma unroll
    for (int r = 0; r < 16; ++r) {
        if (myb[r] >= 0) {
            int pos = lbase[myb[r]] + myloc[r];
            stag[pos] = myp[r];
            stagb[pos] = (u16)myb[r];
        }
    }
    __syncthreads();
    for (int i = t; i < cnt; i += 512) {
        int bb = stagb[i];
        pairs[gbase[bb] + (i - lbase[bb])] = stag[i];
    }
    __threadfence();
    grid.sync();

    // ---- phase 4: per-bucket CSR fill + dinv + fused xs (x * dinv, bf16) ----
    int n0 = b << 8;
    int gb = bucketBase[b];
    int gend = bucketBase[b + 1];
    int nvalid = min(256, NN - n0);

    if (t < 256) sb[t] = 0;
    __syncthreads();
    for (int idx = gb + t; idx < gend; idx += 512) atomicAdd(&sb[pairs[idx] & 255u], 1);
    __syncthreads();
    int d = (t < 256) ? sb[t] : 0;
    if (t < 256) {
        sdeg[t] = d;
        float dn = rsqrtf((float)(d + 1));
        sdinv[t] = dn;
        int n = n0 + t;
        if (n < NN) dinv[n] = dn;
    }
    __syncthreads();
    for (int off = 1; off < 256; off <<= 1) {
        int v = 0;
        if (t < 256 && t >= off) v = sb[t - off];
        __syncthreads();
        if (t < 256) sb[t] += v;
        __syncthreads();
    }
    if (t < 256) {
        int excl = sb[t] - sdeg[t];
        int n = n0 + t;
        if (n < NN) rowptr[n] = gb + excl;
        lcur[t] = excl;
    }
    if (b == 0 && t == 0) rowptr[NN] = EE;
    __syncthreads();
    for (int idx = gb + t; idx < gend; idx += 512) {
        u32 p = pairs[idx];
        int dl = (int)(p & 255u);
        int slot = atomicAdd(&lcur[dl], 1);
        srcS[gb + slot] = (int)(p >> 8);
    }
    // fused xs: 256 nodes * 16 feats = 1024 float4
    for (int q = t; q < nvalid * 4; q += 512) {
        int nloc = q >> 2;
        float dn = sdinv[nloc];
        float4 v = ((const float4*)x)[(size_t)n0 * 4 + q];
        u32 p0 = (u32)f2bf(v.x * dn) | ((u32)f2bf(v.y * dn) << 16);
        u32 p1 = (u32)f2bf(v.z * dn) | ((u32)f2bf(v.w * dn) << 16);
        uint2 pk; pk.x = p0; pk.y = p1;
        ((uint2*)xs)[(size_t)n0 * 4 + q] = pk;
    }
}

#define ACCUM8(acc, v)                       \
    {                                        \
        acc[0] += bf_lo(v.x);                \
        acc[1] += bf_hi(v.x);                \
        acc[2] += bf_lo(v.y);                \
        acc[3] += bf_hi(v.y);                \
        acc[4] += bf_lo(v.z);                \
        acc[5] += bf_hi(v.z);                \
        acc[6] += bf_lo(v.w);                \
        acc[7] += bf_hi(v.w);                \
    }

// folded reduce over lane-bit masks mA<mB<mC: 8 accs -> 1 value per lane.
#define FOLD3(res, acc, mA, mB, mC)                                   \
    {                                                                 \
        float tj[4], uj[2];                                           \
        _Pragma("unroll")                                             \
        for (int j = 0; j < 4; j++) {                                 \
            float lo = acc[j], hi = acc[j + 4];                       \
            float snd = (lane & mA) ? lo : hi;                        \
            float rcv = __shfl_xor(snd, mA);                          \
            tj[j] = (lane & mA) ? hi + rcv : lo + rcv;                \
        }                                                             \
        _Pragma("unroll")                                             \
        for (int j = 0; j < 2; j++) {                                 \
            float lo = tj[j], hi = tj[j + 2];                         \
            float snd = (lane & mB) ? lo : hi;                        \
            float rcv = __shfl_xor(snd, mB);                          \
            uj[j] = (lane & mB) ? hi + rcv : lo + rcv;                \
        }                                                             \
        {                                                             \
            float lo = uj[0], hi = uj[1];                             \
            float snd = (lane & mC) ? lo : hi;                        \
            float rcv = __shfl_xor(snd, mC);                          \
            res = (lane & mC) ? hi + rcv : lo + rcv;                  \
        }                                                             \
    }

// ---------------- pass 1: aggregate 16-dim xs, @W1 +b1, relu, *dinv -> h1d -----------

__global__ __launch_bounds__(256) void aggx_k(const u16* __restrict__ xs,
                                              const int* __restrict__ rowptr,
                                              const int* __restrict__ srcS,
                                              const float* __restrict__ dinv,
                                              const float* __restrict__ b1,
                                              const float* __restrict__ W1,
                                              u16* __restrict__ h1d) {
    int t = threadIdx.x;
    int lane = t & 63, w = t >> 6;
    int c = lane & 1, r = lane >> 1;
    int n0 = blockIdx.x * 8 + w * 2;
    int n1 = n0 + 1;

    float w1c[16];
#pragma unroll
    for (int k = 0; k < 16; k++) w1c[k] = W1[k * HDIM + lane];
    float b1l = b1[lane];

    int beg0 = rowptr[n0], end0 = rowptr[n0 + 1], end1 = rowptr[n0 + 2];
    int beg1 = end0;
    float dn0 = dinv[n0], dn1 = dinv[n1];

    float acc0[8] = {0, 0, 0, 0, 0, 0, 0, 0};
    float acc1[8] = {0, 0, 0, 0, 0, 0, 0, 0};
    if (r == 0) {   // self-loops
        uint4 v0 = *(const uint4*)(xs + ((size_t)n0 << 4) + (c << 3));
        uint4 v1 = *(const uint4*)(xs + ((size_t)n1 << 4) + (c << 3));
        ACCUM8(acc0, v0);
        ACCUM8(acc1, v1);
    }
    int itmax = max((end0 - beg0 + 31) >> 5, (end1 - beg1 + 31) >> 5);
    for (int it = 0; it < itmax; ++it) {
        int eA = beg0 + (it << 5) + r;
        int eB = beg1 + (it << 5) + r;
        int iA = srcS[eA < end0 ? eA : beg0];
        int iB = srcS[eB < end1 ? eB : beg1];
        uint4 vA = *(const uint4*)(xs + ((size_t)iA << 4) + (c << 3));
        uint4 vB = *(const uint4*)(xs + ((size_t)iB << 4) + (c << 3));
        if (eA < end0) ACCUM8(acc0, vA);
        if (eB < end1) ACCUM8(acc1, vB);
    }

    float v0, v1;
    FOLD3(v0, acc0, 2, 4, 8);
    FOLD3(v1, acc1, 2, 4, 8);
    v0 += __shfl_xor(v0, 16); v0 += __shfl_xor(v0, 32);
    v1 += __shfl_xor(v1, 16); v1 += __shfl_xor(v1, 32);

    float dot0 = 0.f, dot1 = 0.f;
#pragma unroll
    for (int k = 0; k < 16; k++) {
        int L = ((k >> 3) & 1) | (((k >> 2) & 1) << 1) | (((k >> 1) & 1) << 2) | ((k & 1) << 3);
        dot0 = fmaf(rdlane(v0, L), w1c[k], dot0);
        dot1 = fmaf(rdlane(v1, L), w1c[k], dot1);
    }
    float h0 = fmaxf(fmaf(dot0, dn0, b1l), 0.f);
    float h1 = fmaxf(fmaf(dot1, dn1, b1l), 0.f);

    h1d[(size_t)n0 * HDIM + lane] = f2bf(h0 * dn0);
    h1d[(size_t)n1 * HDIM + lane] = f2bf(h1 * dn1);
}

// ---------------- MFMA GEMM: h2s = h1d @ W2  (M=NN, N=64, K=64, bf16) ----------------

__global__ __launch_bounds__(256) void gemm_w2_k(const u16* __restrict__ h1d,
                                                 const float* __restrict__ W2,
                                                 u16* __restrict__ h2s) {
    int t = threadIdx.x;
    int lane = t & 63, w = t >> 6;
    int L4 = lane >> 4, L15 = lane & 15;

    bf16x8 bfrag[4][2];
#pragma unroll
    for (int nt = 0; nt < 4; ++nt)
#pragma unroll
        for (int s = 0; s < 2; ++s) {
#pragma unroll
            for (int j = 0; j < 8; ++j) {
                int k = s * 32 + L4 * 8 + j;
                bfrag[nt][s][j] = (short)f2bf(W2[k * HDIM + nt * 16 + L15]);
            }
        }

    int tile0 = (blockIdx.x * 4 + w) * 2;
#pragma unroll
    for (int ti = 0; ti < 2; ++ti) {
        int tile = tile0 + ti;
        if (tile >= NN / 16) break;
        int node = tile * 16 + L15;
        const u16* arow = h1d + (size_t)node * HDIM + L4 * 8;
        bf16x8 a0 = *(const bf16x8*)(arow);
        bf16x8 a1 = *(const bf16x8*)(arow + 32);

        f32x4 c[4];
#pragma unroll
        for (int nt = 0; nt < 4; ++nt) {
            c[nt] = (f32x4){0.f, 0.f, 0.f, 0.f};
            c[nt] = __builtin_amdgcn_mfma_f32_16x16x32_bf16(a0, bfrag[nt][0], c[nt], 0, 0, 0);
            c[nt] = __builtin_amdgcn_mfma_f32_16x16x32_bf16(a1, bfrag[nt][1], c[nt], 0, 0, 0);
        }
#pragma unroll
        for (int q = 0; q < 4; ++q) {
            int row = L4 * 4 + q;
            size_t base = (size_t)(tile * 16 + row) * HDIM + L15;
#pragma unroll
            for (int nt = 0; nt < 4; ++nt) h2s[base + nt * 16] = f2bf(c[nt][q]);
        }
    }
}

// ---------------- pass 2: 64-dim gather + relu + pool with LDS pool pre-reduction ----

__global__ __launch_bounds__(512) void agg_pool_k(const u16* __restrict__ hs,
                                                  const int* __restrict__ rowptr,
                                                  const int* __restrict__ srcS,
                                                  const float* __restrict__ dinv,
                                                  const float* __restrict__ b2,
                                                  const int* __restrict__ batch,
                                                  float* __restrict__ g) {
    __shared__ float gacc[4][HDIM];
    __shared__ int s_g0, s_gmax;
    int t = threadIdx.x;
    int lane = t & 63, w = t >> 6;
    int nbase = blockIdx.x * 32;

    if (t < 4 * HDIM) gacc[t >> 6][t & 63] = 0.f;
    if (t == 0) { s_g0 = batch[nbase]; s_gmax = 0; }
    __syncthreads();
    int g0 = s_g0;

    int r = lane >> 3, c = lane & 7;
    int f = (c << 3) + ((lane & 8) ? 4 : 0) + ((lane & 16) ? 2 : 0) + ((lane & 32) ? 1 : 0);
    float b2f = b2[f];

    for (int ni = 0; ni < 4; ++ni) {
        int n = nbase + w * 4 + ni;
        int beg = rowptr[n], end = rowptr[n + 1];
        float acc[8] = {0.f, 0.f, 0.f, 0.f, 0.f, 0.f, 0.f, 0.f};
        if (r == 0) {   // self-loop
            uint4 v = *(const uint4*)(hs + ((size_t)n << 6) + (c << 3));
            ACCUM8(acc, v);
        }
        for (int e0 = beg; e0 < end; e0 += 32) {
            int eA = e0 + r, eB = eA + 8, eC = eA + 16, eD = eA + 24;
            int iA = srcS[eA < end ? eA : beg];
            int iB = srcS[eB < end ? eB : beg];
            int iC = srcS[eC < end ? eC : beg];
            int iD = srcS[eD < end ? eD : beg];
            uint4 vA = *(const uint4*)(hs + ((size_t)iA << 6) + (c << 3));
            uint4 vB = *(const uint4*)(hs + ((size_t)iB << 6) + (c << 3));
            uint4 vC = *(const uint4*)(hs + ((size_t)iC << 6) + (c << 3));
            uint4 vD = *(const uint4*)(hs + ((size_t)iD << 6) + (c << 3));
            if (eA < end) ACCUM8(acc, vA);
            if (eB < end) ACCUM8(acc, vB);
            if (eC < end) ACCUM8(acc, vC);
            if (eD < end) ACCUM8(acc, vD);
        }
        float red;
        FOLD3(red, acc, 8, 16, 32);
        float v = fmaf(red, dinv[n], b2f);
        v = fmaxf(v, 0.f);
        int gi = batch[n] - g0;
        if (gi < 4) {
            atomicAdd(&gacc[gi][f], v);
            if (lane == 0) atomicMax(&s_gmax, gi);
        } else {
            unsafeAtomicAdd(&g[(size_t)batch[n] * HDIM + f], v);
        }
    }
    __syncthreads();
    if (t < 4 * HDIM) {
        int slot = t >> 6, ff = t & 63;
        if (slot <= s_gmax) unsafeAtomicAdd(&g[(size_t)(g0 + slot) * HDIM + ff], gacc[slot][ff]);
    }
}

__global__ void final_k(const float* __restrict__ g, const float* __restrict__ Wl,
                        const float* __restrict__ bl, float* __restrict__ out) {
    int t = threadIdx.x;
    int gi = t >> 2, cc = t & 3;
    float acc = bl[cc];
#pragma unroll
    for (int k = 0; k < HDIM; k++) acc = fmaf(g[gi * HDIM + k], Wl[k * CDIM + cc], acc);
    out[gi * CDIM + cc] = acc;
}

// ---------------- launch ----------------

extern "C" void kernel_launch(void* const* d_in, const int* in_sizes, int n_in,
                              void* d_out, int out_size, void* d_ws, size_t ws_size,
                              hipStream_t stream) {
    const float* x   = (const float*)d_in[0];
    const int*   ei  = (const int*)d_in[1];
    const int*   src = ei;
    const int*   dst = ei + EE;
    const int*   batch = (const int*)d_in[2];
    const float* W1 = (const float*)d_in[3];
    const float* b1 = (const float*)d_in[4];
    const float* W2 = (const float*)d_in[5];
    const float* b2 = (const float*)d_in[6];
    const float* Wl = (const float*)d_in[7];
    const float* bl = (const float*)d_in[8];
    float* out = (float*)d_out;

    char* w = (char*)d_ws;
    auto alloc = [&](size_t bytes) -> char* {
        char* p = w;
        w += (bytes + 255) & ~(size_t)255;
        return p;
    };
    int*   bcnt       = (int*)alloc((size_t)NB * 4);
    int*   bucketBase = (int*)alloc((size_t)(NB + 1) * 4);
    int*   gcursor    = (int*)alloc((size_t)NB * 4);
    u32*   pairs      = (u32*)alloc((size_t)EE * 4);
    int*   srcS       = (int*)alloc((size_t)EE * 4);
    int*   rowptr     = (int*)alloc((size_t)(NN + 1) * 4);
    float* dinv       = (float*)alloc((size_t)NN * 4);
    u16*   xs         = (u16*)alloc((size_t)NN * IN_DIM * 2);
    u16*   h1d        = (u16*)alloc((size_t)NN * HDIM * 2);
    u16*   h2s        = (u16*)alloc((size_t)NN * HDIM * 2);
    float* g          = (float*)alloc((size_t)GG * HDIM * 4);

    hipMemsetAsync(bcnt, 0, (size_t)NB * 4, stream);
    hipMemsetAsync(g, 0, (size_t)GG * HDIM * 4, stream);

    {
        void* args[] = {(void*)&src, (void*)&dst, (void*)&x, (void*)&bcnt,
                        (void*)&bucketBase, (void*)&gcursor, (void*)&pairs,
                        (void*)&rowptr, (void*)&dinv, (void*)&srcS, (void*)&xs};
        hipLaunchCooperativeKernel((void*)build_k, dim3(NB), dim3(512), args, 0, stream);
    }

    aggx_k<<<NN / 8, 256, 0, stream>>>(xs, rowptr, srcS, dinv, b1, W1, h1d);
    gemm_w2_k<<<(NN / 16 + 7) / 8, 256, 0, stream>>>(h1d, W2, h2s);
    agg_pool_k<<<NN / 32, 512, 0, stream>>>(h2s, rowptr, srcS, dinv, b2, batch, g);
    final_k<<<1, 512, 0, stream>>>(g, Wl, bl, out);
}

// Round 16
// 185.284 us; speedup vs baseline: 2.6237x; 2.6237x over previous
//
#include <hip/hip_runtime.h>
#include <hip/hip_bf16.h>

#define NN 100000
#define EE 3200000
#define GG 128
#define IN_DIM 16
#define HDIM 64
#define CDIM 4

#define RN 256                    // nodes per bucket
#define NB ((NN + RN - 1) / RN)   // 391 buckets
#define CH 8192                   // edges per partition block

typedef unsigned short u16;
typedef unsigned int u32;
typedef __attribute__((ext_vector_type(8))) short bf16x8;
typedef __attribute__((ext_vector_type(4))) float f32x4;

__device__ __forceinline__ float bf_lo(u32 w) { return __uint_as_float(w << 16); }
__device__ __forceinline__ float bf_hi(u32 w) { return __uint_as_float(w & 0xFFFF0000u); }
__device__ __forceinline__ u16 f2bf(float f) {
    u32 x = __float_as_uint(f);
    return (u16)((x + 0x7FFFu + ((x >> 16) & 1u)) >> 16);   // RNE
}
__device__ __forceinline__ int br4(int k) {   // bit-reverse low 4 bits
    return ((k & 1) << 3) | ((k & 2) << 1) | ((k & 4) >> 1) | ((k & 8) >> 3);
}

// ---------------- bucket histogram ----------------

__global__ __launch_bounds__(512) void bhist_k(const int* __restrict__ dst,
                                               int* __restrict__ bcnt) {
    __shared__ int hist[NB];
    int t = threadIdx.x;
    long e0 = (long)blockIdx.x * CH;
    int cnt = (int)min((long)CH, (long)EE - e0);
    for (int i = t; i < NB; i += 512) hist[i] = 0;
    __syncthreads();
    for (int i = t; i < cnt; i += 512) atomicAdd(&hist[dst[e0 + i] >> 8], 1);
    __syncthreads();
    for (int i = t; i < NB; i += 512) {
        int v = hist[i];
        if (v > 0) atomicAdd(&bcnt[i], v);
    }
}

__global__ void bucketscan_k(const int* __restrict__ bcnt, int* __restrict__ bucketBase,
                             int* __restrict__ gcursor) {
    __shared__ int s[512];
    int t = threadIdx.x;
    int c = (t < NB) ? bcnt[t] : 0;
    s[t] = c;
    __syncthreads();
    for (int off = 1; off < 512; off <<= 1) {
        int v = (t >= off) ? s[t - off] : 0;
        __syncthreads();
        s[t] += v;
        __syncthreads();
    }
    if (t < NB) {
        int base = s[t] - c;
        bucketBase[t] = base;
        gcursor[t] = base;
    }
    if (t == 0) bucketBase[NB] = EE;
}

// ---------------- partition: edges -> bucket-grouped packed pairs ----------------

__global__ __launch_bounds__(512) void partition_k(const int* __restrict__ src,
                                                   const int* __restrict__ dst,
                                                   int* __restrict__ gcursor,
                                                   u32* __restrict__ pairs) {
    __shared__ int hist[NB];
    __shared__ int lbase[NB];
    __shared__ int gbase[NB];
    __shared__ int scanbuf[512];
    __shared__ u32 stag[CH];
    __shared__ u16 stagb[CH];
    int t = threadIdx.x;
    long e0 = (long)blockIdx.x * CH;
    int cnt = (int)min((long)CH, (long)EE - e0);

    for (int i = t; i < NB; i += 512) hist[i] = 0;
    __syncthreads();

    int myb[16], myloc[16];
    u32 myp[16];
#pragma unroll
    for (int r = 0; r < 16; ++r) {
        int i = t + (r << 9);
        if (i < cnt) {
            int s = src[e0 + i], d = dst[e0 + i];
            int b = d >> 8;
            myb[r] = b;
            myp[r] = ((u32)s << 8) | (u32)(d & 255);
            myloc[r] = atomicAdd(&hist[b], 1);
        } else {
            myb[r] = -1;
            myloc[r] = 0;
            myp[r] = 0;
        }
    }
    __syncthreads();

    scanbuf[t] = (t < NB) ? hist[t] : 0;
    __syncthreads();
    for (int off = 1; off < 512; off <<= 1) {
        int v = (t >= off) ? scanbuf[t - off] : 0;
        __syncthreads();
        scanbuf[t] += v;
        __syncthreads();
    }
    if (t < NB) {
        lbase[t] = scanbuf[t] - hist[t];
        gbase[t] = (hist[t] > 0) ? atomicAdd(&gcursor[t], hist[t]) : 0;
    }
    __syncthreads();

#pragma unroll
    for (int r = 0; r < 16; ++r) {
        if (myb[r] >= 0) {
            int pos = lbase[myb[r]] + myloc[r];
            stag[pos] = myp[r];
            stagb[pos] = (u16)myb[r];
        }
    }
    __syncthreads();

    for (int i = t; i < cnt; i += 512) {
        int b = stagb[i];
        pairs[gbase[b] + (i - lbase[b])] = stag[i];
    }
}

// ---------------- per-bucket CSR fill ----------------

__global__ __launch_bounds__(512) void csrfill_k(const int* __restrict__ bucketBase,
                                                 const u32* __restrict__ pairs,
                                                 int* __restrict__ rowptr,
                                                 float* __restrict__ dinv,
                                                 int* __restrict__ srcS) {
    __shared__ int sb[256];
    __shared__ int sdeg[256];
    __shared__ int lcur[256];
    int b = blockIdx.x, t = threadIdx.x;
    int n0 = b << 8;
    int gb = bucketBase[b];
    int gend = bucketBase[b + 1];

    if (t < 256) sb[t] = 0;
    __syncthreads();

    for (int idx = gb + t; idx < gend; idx += 512) atomicAdd(&sb[pairs[idx] & 255u], 1);
    __syncthreads();

    int d = (t < 256) ? sb[t] : 0;
    if (t < 256) {
        sdeg[t] = d;
        int n = n0 + t;
        if (n < NN) dinv[n] = rsqrtf((float)(d + 1));
    }
    __syncthreads();
    for (int off = 1; off < 256; off <<= 1) {
        int v = 0;
        if (t < 256 && t >= off) v = sb[t - off];
        __syncthreads();
        if (t < 256) sb[t] += v;
        __syncthreads();
    }
    if (t < 256) {
        int excl = sb[t] - sdeg[t];
        int n = n0 + t;
        if (n < NN) rowptr[n] = gb + excl;
        lcur[t] = excl;
    }
    if (b == 0 && t == 0) rowptr[NN] = EE;
    __syncthreads();

    for (int idx = gb + t; idx < gend; idx += 512) {
        u32 p = pairs[idx];
        int dl = (int)(p & 255u);
        int slot = atomicAdd(&lcur[dl], 1);
        srcS[gb + slot] = (int)(p >> 8);
    }
}

// ---------------- xs = x * dinv, bf16 (3.2 MB table, L2-resident) ----------------

__global__ void xs_k(const float* __restrict__ x, const float* __restrict__ dinv,
                     u16* __restrict__ xs) {
    int i = blockIdx.x * 256 + threadIdx.x;
    if (i >= NN * 4) return;
    int n = i >> 2;
    float dn = dinv[n];
    float4 v = ((const float4*)x)[i];
    u32 p0 = (u32)f2bf(v.x * dn) | ((u32)f2bf(v.y * dn) << 16);
    u32 p1 = (u32)f2bf(v.z * dn) | ((u32)f2bf(v.w * dn) << 16);
    uint2 pk; pk.x = p0; pk.y = p1;
    ((uint2*)xs)[i] = pk;
}

#define ACCUM8(acc, v)                       \
    {                                        \
        acc[0] += bf_lo(v.x);                \
        acc[1] += bf_hi(v.x);                \
        acc[2] += bf_lo(v.y);                \
        acc[3] += bf_hi(v.y);                \
        acc[4] += bf_lo(v.z);                \
        acc[5] += bf_hi(v.z);                \
        acc[6] += bf_lo(v.w);                \
        acc[7] += bf_hi(v.w);                \
    }

// folded reduce over lane-bit masks mA<mB<mC: 8 accs -> 1 value per lane.
#define FOLD3(res, acc, mA, mB, mC)                                   \
    {                                                                 \
        float tj[4], uj[2];                                           \
        _Pragma("unroll")                                             \
        for (int j = 0; j < 4; j++) {                                 \
            float lo = acc[j], hi = acc[j + 4];                       \
            float snd = (lane & mA) ? lo : hi;                        \
            float rcv = __shfl_xor(snd, mA);                          \
            tj[j] = (lane & mA) ? hi + rcv : lo + rcv;                \
        }                                                             \
        _Pragma("unroll")                                             \
        for (int j = 0; j < 2; j++) {                                 \
            float lo = tj[j], hi = tj[j + 2];                         \
            float snd = (lane & mB) ? lo : hi;                        \
            float rcv = __shfl_xor(snd, mB);                          \
            uj[j] = (lane & mB) ? hi + rcv : lo + rcv;                \
        }                                                             \
        {                                                             \
            float lo = uj[0], hi = uj[1];                             \
            float snd = (lane & mC) ? lo : hi;                        \
            float rcv = __shfl_xor(snd, mC);                          \
            res = (lane & mC) ? hi + rcv : lo + rcv;                  \
        }                                                             \
    }

// ---------------- pass 1a: aggregate 16-dim xs -> agg16 (bf16, bitrev4 lane order) ----
// lane: c = lane&1 (16B chunk of 32B row), r = lane>>1 (32 edge slots)
// agg16[n][L] holds feature bitrev4(L); mlp_k compensates via permuted W1 rows.

__global__ __launch_bounds__(256) void aggs_k(const u16* __restrict__ xs,
                                              const int* __restrict__ rowptr,
                                              const int* __restrict__ srcS,
                                              u16* __restrict__ agg16) {
    int t = threadIdx.x;
    int lane = t & 63, w = t >> 6;
    int c = lane & 1, r = lane >> 1;
    int n0 = blockIdx.x * 8 + w * 2;
    int n1 = n0 + 1;

    int beg0 = rowptr[n0], end0 = rowptr[n0 + 1], end1 = rowptr[n0 + 2];
    int beg1 = end0;

    float acc0[8] = {0, 0, 0, 0, 0, 0, 0, 0};
    float acc1[8] = {0, 0, 0, 0, 0, 0, 0, 0};
    if (r == 0) {   // self-loops
        uint4 v0 = *(const uint4*)(xs + ((size_t)n0 << 4) + (c << 3));
        uint4 v1 = *(const uint4*)(xs + ((size_t)n1 << 4) + (c << 3));
        ACCUM8(acc0, v0);
        ACCUM8(acc1, v1);
    }
    int itmax = max((end0 - beg0 + 31) >> 5, (end1 - beg1 + 31) >> 5);
    for (int it = 0; it < itmax; ++it) {
        int eA = beg0 + (it << 5) + r;
        int eB = beg1 + (it << 5) + r;
        int iA = srcS[eA < end0 ? eA : beg0];
        int iB = srcS[eB < end1 ? eB : beg1];
        uint4 vA = *(const uint4*)(xs + ((size_t)iA << 4) + (c << 3));
        uint4 vB = *(const uint4*)(xs + ((size_t)iB << 4) + (c << 3));
        if (eA < end0) ACCUM8(acc0, vA);
        if (eB < end1) ACCUM8(acc1, vB);
    }

    float v0, v1;
    FOLD3(v0, acc0, 2, 4, 8);
    FOLD3(v1, acc1, 2, 4, 8);
    v0 += __shfl_xor(v0, 16); v0 += __shfl_xor(v0, 32);
    v1 += __shfl_xor(v1, 16); v1 += __shfl_xor(v1, 32);
    // lanes L, L+16, L+32, L+48 hold identical values; feature = bitrev4(L&15)

    if (lane < 32) {
        float v = (lane < 16) ? v0 : v1;
        int n = (lane < 16) ? n0 : n1;
        agg16[(size_t)n * 16 + (lane & 15)] = f2bf(v);
    }
}

// ---------------- pass 1b (MFMA): h2s = (relu(dinv*(agg16@W1)+b1)*dinv) @ W2 ----------
// Per 16-node tile: stage 1 = mfma_16x16x32 (K=32, upper-16 zero-padded, W1 rows
// bitrev4-permuted to match agg16 lane order); epilogue relu/bias/dinv -> wave-private
// LDS tile; stage 2 = 2x mfma per N-tile with W2 (same layout as verified gemm_w2_k).
// No barriers: each wave owns its LDS region; DS ops are in-order per wave.

__global__ __launch_bounds__(256) void mlp_k(const u16* __restrict__ agg16,
                                             const float* __restrict__ dinv,
                                             const float* __restrict__ b1,
                                             const float* __restrict__ W1,
                                             const float* __restrict__ W2,
                                             u16* __restrict__ h2s) {
    __shared__ u16 atile[4][16][72];
    int t = threadIdx.x;
    int lane = t & 63, w = t >> 6;
    int L4 = lane >> 4, L15 = lane & 15;

    // W1 fragments: K=32 (k<16 real, permuted rows; k>=16 zero)
    bf16x8 w1frag[4];
#pragma unroll
    for (int nt = 0; nt < 4; ++nt) {
#pragma unroll
        for (int j = 0; j < 8; ++j) {
            int k = L4 * 8 + j;
            w1frag[nt][j] = (k < 16) ? (short)f2bf(W1[br4(k) * HDIM + nt * 16 + L15])
                                     : (short)0;
        }
    }
    // W2 fragments (as gemm_w2_k)
    bf16x8 w2frag[4][2];
#pragma unroll
    for (int nt = 0; nt < 4; ++nt)
#pragma unroll
        for (int s = 0; s < 2; ++s) {
#pragma unroll
            for (int j = 0; j < 8; ++j) {
                int k = s * 32 + L4 * 8 + j;
                w2frag[nt][s][j] = (short)f2bf(W2[k * HDIM + nt * 16 + L15]);
            }
        }
    float b1l[4];
#pragma unroll
    for (int nt = 0; nt < 4; ++nt) b1l[nt] = b1[nt * 16 + L15];

    int tile0 = (blockIdx.x * 4 + w) * 2;
#pragma unroll
    for (int ti = 0; ti < 2; ++ti) {
        int tile = tile0 + ti;
        if (tile >= NN / 16) break;
        int row16 = tile * 16;

        // stage 1: A = agg16 tile (node = L15, k-chunk = L4; zero for k>=16)
        bf16x8 a = (bf16x8)(short)0;
        if (L4 < 2) a = *(const bf16x8*)(agg16 + ((size_t)(row16 + L15) << 4) + L4 * 8);
        f32x4 c[4];
#pragma unroll
        for (int nt = 0; nt < 4; ++nt) {
            c[nt] = (f32x4){0.f, 0.f, 0.f, 0.f};
            c[nt] = __builtin_amdgcn_mfma_f32_16x16x32_bf16(a, w1frag[nt], c[nt], 0, 0, 0);
        }
        // epilogue: h = relu(dot*dinv + b1) * dinv -> LDS (row = node, col = feature)
        float dn[4];
#pragma unroll
        for (int q = 0; q < 4; ++q) dn[q] = dinv[row16 + L4 * 4 + q];
#pragma unroll
        for (int q = 0; q < 4; ++q) {
            int row = L4 * 4 + q;
#pragma unroll
            for (int nt = 0; nt < 4; ++nt) {
                float h = fmaxf(fmaf(c[nt][q], dn[q], b1l[nt]), 0.f) * dn[q];
                atile[w][row][nt * 16 + L15] = f2bf(h);
            }
        }
        // stage 2: A from LDS tile (node = L15), B = W2
        bf16x8 a0 = *(const bf16x8*)&atile[w][L15][L4 * 8];
        bf16x8 a1 = *(const bf16x8*)&atile[w][L15][L4 * 8 + 32];
        f32x4 cc[4];
#pragma unroll
        for (int nt = 0; nt < 4; ++nt) {
            cc[nt] = (f32x4){0.f, 0.f, 0.f, 0.f};
            cc[nt] = __builtin_amdgcn_mfma_f32_16x16x32_bf16(a0, w2frag[nt][0], cc[nt], 0, 0, 0);
            cc[nt] = __builtin_amdgcn_mfma_f32_16x16x32_bf16(a1, w2frag[nt][1], cc[nt], 0, 0, 0);
        }
#pragma unroll
        for (int q = 0; q < 4; ++q) {
            int row = L4 * 4 + q;
            size_t base = (size_t)(row16 + row) * HDIM + L15;
#pragma unroll
            for (int nt = 0; nt < 4; ++nt) h2s[base + nt * 16] = f2bf(cc[nt][q]);
        }
    }
}

// ---------------- pass 2: 64-dim gather + relu + pool with LDS pool pre-reduction ----

__global__ __launch_bounds__(512) void agg_pool_k(const u16* __restrict__ hs,
                                                  const int* __restrict__ rowptr,
                                                  const int* __restrict__ srcS,
                                                  const float* __restrict__ dinv,
                                                  const float* __restrict__ b2,
                                                  const int* __restrict__ batch,
                                                  float* __restrict__ g) {
    __shared__ float gacc[4][HDIM];
    __shared__ int s_g0, s_gmax;
    int t = threadIdx.x;
    int lane = t & 63, w = t >> 6;
    int nbase = blockIdx.x * 32;

    if (t < 4 * HDIM) gacc[t >> 6][t & 63] = 0.f;
    if (t == 0) { s_g0 = batch[nbase]; s_gmax = 0; }
    __syncthreads();
    int g0 = s_g0;

    int r = lane >> 3, c = lane & 7;
    int f = (c << 3) + ((lane & 8) ? 4 : 0) + ((lane & 16) ? 2 : 0) + ((lane & 32) ? 1 : 0);
    float b2f = b2[f];

    for (int ni = 0; ni < 4; ++ni) {
        int n = nbase + w * 4 + ni;
        int beg = rowptr[n], end = rowptr[n + 1];
        float acc[8] = {0.f, 0.f, 0.f, 0.f, 0.f, 0.f, 0.f, 0.f};
        if (r == 0) {   // self-loop
            uint4 v = *(const uint4*)(hs + ((size_t)n << 6) + (c << 3));
            ACCUM8(acc, v);
        }
        for (int e0 = beg; e0 < end; e0 += 32) {
            int eA = e0 + r, eB = eA + 8, eC = eA + 16, eD = eA + 24;
            int iA = srcS[eA < end ? eA : beg];
            int iB = srcS[eB < end ? eB : beg];
            int iC = srcS[eC < end ? eC : beg];
            int iD = srcS[eD < end ? eD : beg];
            uint4 vA = *(const uint4*)(hs + ((size_t)iA << 6) + (c << 3));
            uint4 vB = *(const uint4*)(hs + ((size_t)iB << 6) + (c << 3));
            uint4 vC = *(const uint4*)(hs + ((size_t)iC << 6) + (c << 3));
            uint4 vD = *(const uint4*)(hs + ((size_t)iD << 6) + (c << 3));
            if (eA < end) ACCUM8(acc, vA);
            if (eB < end) ACCUM8(acc, vB);
            if (eC < end) ACCUM8(acc, vC);
            if (eD < end) ACCUM8(acc, vD);
        }
        float red;
        FOLD3(red, acc, 8, 16, 32);
        float v = fmaf(red, dinv[n], b2f);
        v = fmaxf(v, 0.f);
        int gi = batch[n] - g0;
        if (gi < 4) {
            atomicAdd(&gacc[gi][f], v);
            if (lane == 0) atomicMax(&s_gmax, gi);
        } else {
            unsafeAtomicAdd(&g[(size_t)batch[n] * HDIM + f], v);
        }
    }
    __syncthreads();
    if (t < 4 * HDIM) {
        int slot = t >> 6, ff = t & 63;
        if (slot <= s_gmax) unsafeAtomicAdd(&g[(size_t)(g0 + slot) * HDIM + ff], gacc[slot][ff]);
    }
}

__global__ void final_k(const float* __restrict__ g, const float* __restrict__ Wl,
                        const float* __restrict__ bl, float* __restrict__ out) {
    int t = threadIdx.x;
    int gi = t >> 2, cc = t & 3;
    float acc = bl[cc];
#pragma unroll
    for (int k = 0; k < HDIM; k++) acc = fmaf(g[gi * HDIM + k], Wl[k * CDIM + cc], acc);
    out[gi * CDIM + cc] = acc;
}

// ---------------- launch ----------------

extern "C" void kernel_launch(void* const* d_in, const int* in_sizes, int n_in,
                              void* d_out, int out_size, void* d_ws, size_t ws_size,
                              hipStream_t stream) {
    const float* x   = (const float*)d_in[0];
    const int*   ei  = (const int*)d_in[1];
    const int*   src = ei;
    const int*   dst = ei + EE;
    const int*   batch = (const int*)d_in[2];
    const float* W1 = (const float*)d_in[3];
    const float* b1 = (const float*)d_in[4];
    const float* W2 = (const float*)d_in[5];
    const float* b2 = (const float*)d_in[6];
    const float* Wl = (const float*)d_in[7];
    const float* bl = (const float*)d_in[8];
    float* out = (float*)d_out;

    char* w = (char*)d_ws;
    auto alloc = [&](size_t bytes) -> char* {
        char* p = w;
        w += (bytes + 255) & ~(size_t)255;
        return p;
    };
    int*   bcnt       = (int*)alloc((size_t)NB * 4);
    int*   bucketBase = (int*)alloc((size_t)(NB + 1) * 4);
    int*   gcursor    = (int*)alloc((size_t)NB * 4);
    u32*   pairs      = (u32*)alloc((size_t)EE * 4);
    int*   srcS       = (int*)alloc((size_t)EE * 4);
    int*   rowptr     = (int*)alloc((size_t)(NN + 1) * 4);
    float* dinv       = (float*)alloc((size_t)NN * 4);
    u16*   xs         = (u16*)alloc((size_t)NN * IN_DIM * 2);
    u16*   agg16      = (u16*)alloc((size_t)NN * 16 * 2);
    u16*   h2s        = (u16*)alloc((size_t)NN * HDIM * 2);
    float* g          = (float*)alloc((size_t)GG * HDIM * 4);

    hipMemsetAsync(bcnt, 0, (size_t)NB * 4, stream);
    hipMemsetAsync(g, 0, (size_t)GG * HDIM * 4, stream);

    const int NCHUNK = (EE + CH - 1) / CH;
    bhist_k<<<NCHUNK, 512, 0, stream>>>(dst, bcnt);
    bucketscan_k<<<1, 512, 0, stream>>>(bcnt, bucketBase, gcursor);
    partition_k<<<NCHUNK, 512, 0, stream>>>(src, dst, gcursor, pairs);
    csrfill_k<<<NB, 512, 0, stream>>>(bucketBase, pairs, rowptr, dinv, srcS);

    xs_k<<<(NN * 4 + 255) / 256, 256, 0, stream>>>(x, dinv, xs);
    aggs_k<<<NN / 8, 256, 0, stream>>>(xs, rowptr, srcS, agg16);
    mlp_k<<<(NN / 16 + 7) / 8, 256, 0, stream>>>(agg16, dinv, b1, W1, W2, h2s);
    agg_pool_k<<<NN / 32, 512, 0, stream>>>(h2s, rowptr, srcS, dinv, b2, batch, g);
    final_k<<<1, 512, 0, stream>>>(g, Wl, bl, out);
}

// Round 17
// 161.439 us; speedup vs baseline: 3.0113x; 1.1477x over previous
//
#include <hip/hip_runtime.h>
#include <hip/hip_bf16.h>

#define NN 100000
#define EE 3200000
#define GG 128
#define IN_DIM 16
#define HDIM 64
#define CDIM 4

#define RN 256                    // nodes per bucket
#define NB ((NN + RN - 1) / RN)   // 391 buckets
#define CH 8192                   // edges per partition chunk
#define CAP 10240                 // fixed bucket capacity (avg 8184, +23 sigma margin)

typedef unsigned short u16;
typedef unsigned int u32;
typedef __attribute__((ext_vector_type(8))) short bf16x8;
typedef __attribute__((ext_vector_type(4))) float f32x4;

__device__ __forceinline__ float bf_lo(u32 w) { return __uint_as_float(w << 16); }
__device__ __forceinline__ float bf_hi(u32 w) { return __uint_as_float(w & 0xFFFF0000u); }
__device__ __forceinline__ u16 f2bf(float f) {
    u32 x = __float_as_uint(f);
    return (u16)((x + 0x7FFFu + ((x >> 16) & 1u)) >> 16);   // RNE
}
__device__ __forceinline__ float rdlane(float v, int lane) {
    return __int_as_float(__builtin_amdgcn_readlane(__float_as_int(v), lane));
}

// ---------------- init: gcursor[b] = b*CAP ----------------

__global__ void init_k(int* __restrict__ gcursor) {
    int t = threadIdx.x;
    if (t < NB) gcursor[t] = t * CAP;
}

// ---------------- partition: edges -> fixed-capacity bucket regions ----------------

__global__ __launch_bounds__(512) void partition_k(const int* __restrict__ src,
                                                   const int* __restrict__ dst,
                                                   int* __restrict__ gcursor,
                                                   u32* __restrict__ pairs) {
    __shared__ int hist[NB];
    __shared__ int lbase[NB];
    __shared__ int gbase[NB];
    __shared__ int scanbuf[512];
    __shared__ u32 stag[CH];
    __shared__ u16 stagb[CH];
    int t = threadIdx.x;
    long e0 = (long)blockIdx.x * CH;
    int cnt = (int)min((long)CH, (long)EE - e0);

    for (int i = t; i < NB; i += 512) hist[i] = 0;
    __syncthreads();

    int myb[16], myloc[16];
    u32 myp[16];
#pragma unroll
    for (int r = 0; r < 16; ++r) {
        int i = t + (r << 9);
        if (i < cnt) {
            int s = src[e0 + i], d = dst[e0 + i];
            int b = d >> 8;
            myb[r] = b;
            myp[r] = ((u32)s << 8) | (u32)(d & 255);
            myloc[r] = atomicAdd(&hist[b], 1);
        } else {
            myb[r] = -1;
            myloc[r] = 0;
            myp[r] = 0;
        }
    }
    __syncthreads();

    scanbuf[t] = (t < NB) ? hist[t] : 0;
    __syncthreads();
    for (int off = 1; off < 512; off <<= 1) {
        int v = (t >= off) ? scanbuf[t - off] : 0;
        __syncthreads();
        scanbuf[t] += v;
        __syncthreads();
    }
    if (t < NB) {
        lbase[t] = scanbuf[t] - hist[t];
        gbase[t] = (hist[t] > 0) ? atomicAdd(&gcursor[t], hist[t]) : 0;
    }
    __syncthreads();

#pragma unroll
    for (int r = 0; r < 16; ++r) {
        if (myb[r] >= 0) {
            int pos = lbase[myb[r]] + myloc[r];
            stag[pos] = myp[r];
            stagb[pos] = (u16)myb[r];
        }
    }
    __syncthreads();

    for (int i = t; i < cnt; i += 512) {
        int b = stagb[i];
        pairs[gbase[b] + (i - lbase[b])] = stag[i];
    }
}

// ---------------- per-bucket CSR fill + dinv + rowrange + fused xs ----------------

__global__ __launch_bounds__(512) void csrfill_k(const int* __restrict__ gcursor,
                                                 const u32* __restrict__ pairs,
                                                 const float* __restrict__ x,
                                                 int2* __restrict__ rowrange,
                                                 float* __restrict__ dinv,
                                                 int* __restrict__ srcS,
                                                 u16* __restrict__ xs) {
    __shared__ int sb[256];
    __shared__ int sdeg[256];
    __shared__ int lcur[256];
    __shared__ float sdinv[256];
    int b = blockIdx.x, t = threadIdx.x;
    int n0 = b << 8;
    int gb = b * CAP;
    int gend = gcursor[b];
    int nvalid = min(256, NN - n0);

    if (t < 256) sb[t] = 0;
    __syncthreads();

    for (int idx = gb + t; idx < gend; idx += 512) atomicAdd(&sb[pairs[idx] & 255u], 1);
    __syncthreads();

    int d = (t < 256) ? sb[t] : 0;
    if (t < 256) {
        sdeg[t] = d;
        float dn = rsqrtf((float)(d + 1));
        sdinv[t] = dn;
        int n = n0 + t;
        if (n < NN) dinv[n] = dn;
    }
    __syncthreads();
    for (int off = 1; off < 256; off <<= 1) {
        int v = 0;
        if (t < 256 && t >= off) v = sb[t - off];
        __syncthreads();
        if (t < 256) sb[t] += v;
        __syncthreads();
    }
    if (t < 256) {
        int excl = sb[t] - sdeg[t];
        int n = n0 + t;
        if (n < NN) {
            int2 rr; rr.x = gb + excl; rr.y = gb + excl + sdeg[t];
            rowrange[n] = rr;
        }
        lcur[t] = excl;
    }
    __syncthreads();

    for (int idx = gb + t; idx < gend; idx += 512) {
        u32 p = pairs[idx];
        int dl = (int)(p & 255u);
        int slot = atomicAdd(&lcur[dl], 1);
        srcS[gb + slot] = (int)(p >> 8);
    }

    // fused xs: nvalid nodes * 16 feats; thread t handles float4 q
    for (int q = t; q < nvalid * 4; q += 512) {
        int nloc = q >> 2;
        float dn = sdinv[nloc];
        float4 v = ((const float4*)x)[(size_t)n0 * 4 + q];
        u32 p0 = (u32)f2bf(v.x * dn) | ((u32)f2bf(v.y * dn) << 16);
        u32 p1 = (u32)f2bf(v.z * dn) | ((u32)f2bf(v.w * dn) << 16);
        uint2 pk; pk.x = p0; pk.y = p1;
        ((uint2*)xs)[(size_t)n0 * 4 + q] = pk;
    }
}

#define ACCUM8(acc, v)                       \
    {                                        \
        acc[0] += bf_lo(v.x);                \
        acc[1] += bf_hi(v.x);                \
        acc[2] += bf_lo(v.y);                \
        acc[3] += bf_hi(v.y);                \
        acc[4] += bf_lo(v.z);                \
        acc[5] += bf_hi(v.z);                \
        acc[6] += bf_lo(v.w);                \
        acc[7] += bf_hi(v.w);                \
    }

// folded reduce over lane-bit masks mA<mB<mC: 8 accs -> 1 value per lane.
#define FOLD3(res, acc, mA, mB, mC)                                   \
    {                                                                 \
        float tj[4], uj[2];                                           \
        _Pragma("unroll")                                             \
        for (int j = 0; j < 4; j++) {                                 \
            float lo = acc[j], hi = acc[j + 4];                       \
            float snd = (lane & mA) ? lo : hi;                        \
            float rcv = __shfl_xor(snd, mA);                          \
            tj[j] = (lane & mA) ? hi + rcv : lo + rcv;                \
        }                                                             \
        _Pragma("unroll")                                             \
        for (int j = 0; j < 2; j++) {                                 \
            float lo = tj[j], hi = tj[j + 2];                         \
            float snd = (lane & mB) ? lo : hi;                        \
            float rcv = __shfl_xor(snd, mB);                          \
            uj[j] = (lane & mB) ? hi + rcv : lo + rcv;                \
        }                                                             \
        {                                                             \
            float lo = uj[0], hi = uj[1];                             \
            float snd = (lane & mC) ? lo : hi;                        \
            float rcv = __shfl_xor(snd, mC);                          \
            res = (lane & mC) ? hi + rcv : lo + rcv;                  \
        }                                                             \
    }

// ---------------- pass 1: aggregate 16-dim xs, @W1 +b1, relu, *dinv -> h1d -----------

__global__ __launch_bounds__(256) void aggx_k(const u16* __restrict__ xs,
                                              const int2* __restrict__ rowrange,
                                              const int* __restrict__ srcS,
                                              const float* __restrict__ dinv,
                                              const float* __restrict__ b1,
                                              const float* __restrict__ W1,
                                              u16* __restrict__ h1d) {
    int t = threadIdx.x;
    int lane = t & 63, w = t >> 6;
    int c = lane & 1, r = lane >> 1;
    int n0 = blockIdx.x * 8 + w * 2;
    int n1 = n0 + 1;

    float w1c[16];
#pragma unroll
    for (int k = 0; k < 16; k++) w1c[k] = W1[k * HDIM + lane];
    float b1l = b1[lane];

    int2 rr0 = rowrange[n0];
    int2 rr1 = rowrange[n1];
    int beg0 = rr0.x, end0 = rr0.y;
    int beg1 = rr1.x, end1 = rr1.y;
    float dn0 = dinv[n0], dn1 = dinv[n1];

    float acc0[8] = {0, 0, 0, 0, 0, 0, 0, 0};
    float acc1[8] = {0, 0, 0, 0, 0, 0, 0, 0};
    if (r == 0) {   // self-loops
        uint4 v0 = *(const uint4*)(xs + ((size_t)n0 << 4) + (c << 3));
        uint4 v1 = *(const uint4*)(xs + ((size_t)n1 << 4) + (c << 3));
        ACCUM8(acc0, v0);
        ACCUM8(acc1, v1);
    }
    int itmax = max((end0 - beg0 + 31) >> 5, (end1 - beg1 + 31) >> 5);
    for (int it = 0; it < itmax; ++it) {
        int eA = beg0 + (it << 5) + r;
        int eB = beg1 + (it << 5) + r;
        int iA = srcS[eA < end0 ? eA : beg0];
        int iB = srcS[eB < end1 ? eB : beg1];
        uint4 vA = *(const uint4*)(xs + ((size_t)iA << 4) + (c << 3));
        uint4 vB = *(const uint4*)(xs + ((size_t)iB << 4) + (c << 3));
        if (eA < end0) ACCUM8(acc0, vA);
        if (eB < end1) ACCUM8(acc1, vB);
    }

    float v0, v1;
    FOLD3(v0, acc0, 2, 4, 8);
    FOLD3(v1, acc1, 2, 4, 8);
    v0 += __shfl_xor(v0, 16); v0 += __shfl_xor(v0, 32);
    v1 += __shfl_xor(v1, 16); v1 += __shfl_xor(v1, 32);

    float dot0 = 0.f, dot1 = 0.f;
#pragma unroll
    for (int k = 0; k < 16; k++) {
        int L = ((k >> 3) & 1) | (((k >> 2) & 1) << 1) | (((k >> 1) & 1) << 2) | ((k & 1) << 3);
        dot0 = fmaf(rdlane(v0, L), w1c[k], dot0);
        dot1 = fmaf(rdlane(v1, L), w1c[k], dot1);
    }
    float h0 = fmaxf(fmaf(dot0, dn0, b1l), 0.f);
    float h1 = fmaxf(fmaf(dot1, dn1, b1l), 0.f);

    h1d[(size_t)n0 * HDIM + lane] = f2bf(h0 * dn0);
    h1d[(size_t)n1 * HDIM + lane] = f2bf(h1 * dn1);
}

// ---------------- MFMA GEMM: h2s = h1d @ W2  (M=NN, N=64, K=64, bf16) ----------------

__global__ __launch_bounds__(256) void gemm_w2_k(const u16* __restrict__ h1d,
                                                 const float* __restrict__ W2,
                                                 u16* __restrict__ h2s) {
    int t = threadIdx.x;
    int lane = t & 63, w = t >> 6;
    int L4 = lane >> 4, L15 = lane & 15;

    bf16x8 bfrag[4][2];
#pragma unroll
    for (int nt = 0; nt < 4; ++nt)
#pragma unroll
        for (int s = 0; s < 2; ++s) {
#pragma unroll
            for (int j = 0; j < 8; ++j) {
                int k = s * 32 + L4 * 8 + j;
                bfrag[nt][s][j] = (short)f2bf(W2[k * HDIM + nt * 16 + L15]);
            }
        }

    int tile0 = (blockIdx.x * 4 + w) * 2;
#pragma unroll
    for (int ti = 0; ti < 2; ++ti) {
        int tile = tile0 + ti;
        if (tile >= NN / 16) break;
        int node = tile * 16 + L15;
        const u16* arow = h1d + (size_t)node * HDIM + L4 * 8;
        bf16x8 a0 = *(const bf16x8*)(arow);
        bf16x8 a1 = *(const bf16x8*)(arow + 32);

        f32x4 c[4];
#pragma unroll
        for (int nt = 0; nt < 4; ++nt) {
            c[nt] = (f32x4){0.f, 0.f, 0.f, 0.f};
            c[nt] = __builtin_amdgcn_mfma_f32_16x16x32_bf16(a0, bfrag[nt][0], c[nt], 0, 0, 0);
            c[nt] = __builtin_amdgcn_mfma_f32_16x16x32_bf16(a1, bfrag[nt][1], c[nt], 0, 0, 0);
        }
#pragma unroll
        for (int q = 0; q < 4; ++q) {
            int row = L4 * 4 + q;
            size_t base = (size_t)(tile * 16 + row) * HDIM + L15;
#pragma unroll
            for (int nt = 0; nt < 4; ++nt) h2s[base + nt * 16] = f2bf(c[nt][q]);
        }
    }
}

// ---------------- pass 2: 64-dim gather + relu + pool with LDS pool pre-reduction ----

__global__ __launch_bounds__(512) void agg_pool_k(const u16* __restrict__ hs,
                                                  const int2* __restrict__ rowrange,
                                                  const int* __restrict__ srcS,
                                                  const float* __restrict__ dinv,
                                                  const float* __restrict__ b2,
                                                  const int* __restrict__ batch,
                                                  float* __restrict__ g) {
    __shared__ float gacc[4][HDIM];
    __shared__ int s_g0, s_gmax;
    int t = threadIdx.x;
    int lane = t & 63, w = t >> 6;
    int nbase = blockIdx.x * 32;

    if (t < 4 * HDIM) gacc[t >> 6][t & 63] = 0.f;
    if (t == 0) { s_g0 = batch[nbase]; s_gmax = 0; }
    __syncthreads();
    int g0 = s_g0;

    int r = lane >> 3, c = lane & 7;
    int f = (c << 3) + ((lane & 8) ? 4 : 0) + ((lane & 16) ? 2 : 0) + ((lane & 32) ? 1 : 0);
    float b2f = b2[f];

    for (int ni = 0; ni < 4; ++ni) {
        int n = nbase + w * 4 + ni;
        int2 rr = rowrange[n];
        int beg = rr.x, end = rr.y;
        float acc[8] = {0.f, 0.f, 0.f, 0.f, 0.f, 0.f, 0.f, 0.f};
        if (r == 0) {   // self-loop
            uint4 v = *(const uint4*)(hs + ((size_t)n << 6) + (c << 3));
            ACCUM8(acc, v);
        }
        for (int e0 = beg; e0 < end; e0 += 32) {
            int eA = e0 + r, eB = eA + 8, eC = eA + 16, eD = eA + 24;
            int iA = srcS[eA < end ? eA : beg];
            int iB = srcS[eB < end ? eB : beg];
            int iC = srcS[eC < end ? eC : beg];
            int iD = srcS[eD < end ? eD : beg];
            uint4 vA = *(const uint4*)(hs + ((size_t)iA << 6) + (c << 3));
            uint4 vB = *(const uint4*)(hs + ((size_t)iB << 6) + (c << 3));
            uint4 vC = *(const uint4*)(hs + ((size_t)iC << 6) + (c << 3));
            uint4 vD = *(const uint4*)(hs + ((size_t)iD << 6) + (c << 3));
            if (eA < end) ACCUM8(acc, vA);
            if (eB < end) ACCUM8(acc, vB);
            if (eC < end) ACCUM8(acc, vC);
            if (eD < end) ACCUM8(acc, vD);
        }
        float red;
        FOLD3(red, acc, 8, 16, 32);
        float v = fmaf(red, dinv[n], b2f);
        v = fmaxf(v, 0.f);
        int gi = batch[n] - g0;
        if (gi < 4) {
            atomicAdd(&gacc[gi][f], v);
            if (lane == 0) atomicMax(&s_gmax, gi);
        } else {
            unsafeAtomicAdd(&g[(size_t)batch[n] * HDIM + f], v);
        }
    }
    __syncthreads();
    if (t < 4 * HDIM) {
        int slot = t >> 6, ff = t & 63;
        if (slot <= s_gmax) unsafeAtomicAdd(&g[(size_t)(g0 + slot) * HDIM + ff], gacc[slot][ff]);
    }
}

__global__ void final_k(const float* __restrict__ g, const float* __restrict__ Wl,
                        const float* __restrict__ bl, float* __restrict__ out) {
    int t = threadIdx.x;
    int gi = t >> 2, cc = t & 3;
    float acc = bl[cc];
#pragma unroll
    for (int k = 0; k < HDIM; k++) acc = fmaf(g[gi * HDIM + k], Wl[k * CDIM + cc], acc);
    out[gi * CDIM + cc] = acc;
}

// ---------------- launch ----------------

extern "C" void kernel_launch(void* const* d_in, const int* in_sizes, int n_in,
                              void* d_out, int out_size, void* d_ws, size_t ws_size,
                              hipStream_t stream) {
    const float* x   = (const float*)d_in[0];
    const int*   ei  = (const int*)d_in[1];
    const int*   src = ei;
    const int*   dst = ei + EE;
    const int*   batch = (const int*)d_in[2];
    const float* W1 = (const float*)d_in[3];
    const float* b1 = (const float*)d_in[4];
    const float* W2 = (const float*)d_in[5];
    const float* b2 = (const float*)d_in[6];
    const float* Wl = (const float*)d_in[7];
    const float* bl = (const float*)d_in[8];
    float* out = (float*)d_out;

    char* w = (char*)d_ws;
    auto alloc = [&](size_t bytes) -> char* {
        char* p = w;
        w += (bytes + 255) & ~(size_t)255;
        return p;
    };
    int*   gcursor  = (int*)alloc((size_t)NB * 4);
    u32*   pairs    = (u32*)alloc((size_t)NB * CAP * 4);
    int*   srcS     = (int*)alloc((size_t)NB * CAP * 4);
    int2*  rowrange = (int2*)alloc((size_t)NN * 8);
    float* dinv     = (float*)alloc((size_t)NN * 4);
    u16*   xs       = (u16*)alloc((size_t)NN * IN_DIM * 2);
    u16*   h1d      = (u16*)alloc((size_t)NN * HDIM * 2);
    u16*   h2s      = (u16*)alloc((size_t)NN * HDIM * 2);
    float* g        = (float*)alloc((size_t)GG * HDIM * 4);

    hipMemsetAsync(g, 0, (size_t)GG * HDIM * 4, stream);

    const int NCHUNK = (EE + CH - 1) / CH;
    init_k<<<1, 512, 0, stream>>>(gcursor);
    partition_k<<<NCHUNK, 512, 0, stream>>>(src, dst, gcursor, pairs);
    csrfill_k<<<NB, 512, 0, stream>>>(gcursor, pairs, x, rowrange, dinv, srcS, xs);

    aggx_k<<<NN / 8, 256, 0, stream>>>(xs, rowrange, srcS, dinv, b1, W1, h1d);
    gemm_w2_k<<<(NN / 16 + 7) / 8, 256, 0, stream>>>(h1d, W2, h2s);
    agg_pool_k<<<NN / 32, 512, 0, stream>>>(h2s, rowrange, srcS, dinv, b2, batch, g);
    final_k<<<1, 512, 0, stream>>>(g, Wl, bl, out);
}